// Round 1
// baseline (1011.982 us; speedup 1.0000x reference)
//
#include <hip/hip_runtime.h>
#include <hip/hip_bf16.h>

typedef __attribute__((ext_vector_type(8))) short bf16x8;
typedef __attribute__((ext_vector_type(4))) float f32x4;

#define S 2048
#define DM 1024
#define NH 16
#define B_ 2

struct __align__(8) us4 { unsigned short a, b, c, d; };

static __device__ __forceinline__ unsigned short f2bf(float f) {
  unsigned int u = __builtin_bit_cast(unsigned int, f);
  u += 0x7fffu + ((u >> 16) & 1u);
  return (unsigned short)(u >> 16);
}

// ---------------- fp32 -> bf16 elementwise ----------------
__global__ __launch_bounds__(256) void k_cvt(const float* __restrict__ x,
                                             unsigned short* __restrict__ y, int n) {
  int i = (blockIdx.x * 256 + threadIdx.x) * 4;
  if (i >= n) return;
  float4 v = *(const float4*)(x + i);
  us4 o; o.a = f2bf(v.x); o.b = f2bf(v.y); o.c = f2bf(v.z); o.d = f2bf(v.w);
  *(us4*)(y + i) = o;
}

// ---------------- W[K][N] fp32 -> Wt[N][K] bf16 ----------------
__global__ __launch_bounds__(256) void k_wtr(const float* __restrict__ W,
                                             unsigned short* __restrict__ Wt) {
  __shared__ float tile[32][33];
  int n0 = blockIdx.x * 32, k0 = blockIdx.y * 32;
  int t = threadIdx.x;
  int r = t >> 3, c = (t & 7) * 4;
  float4 v = *(const float4*)(W + (long)(k0 + r) * DM + n0 + c);
  tile[r][c] = v.x; tile[r][c + 1] = v.y; tile[r][c + 2] = v.z; tile[r][c + 3] = v.w;
  __syncthreads();
  us4 o;
  o.a = f2bf(tile[c][r]); o.b = f2bf(tile[c + 1][r]);
  o.c = f2bf(tile[c + 2][r]); o.d = f2bf(tile[c + 3][r]);
  *(us4*)(Wt + (long)(n0 + r) * DM + k0 + c) = o;
}

// ---------------- NT GEMM: C[M,N] = A[M,K] @ Bt[N,K]^T (bf16 in) ----------------
template <int F32OUT>
__global__ __launch_bounds__(256) void k_gemm_nt(const unsigned short* __restrict__ A,
                                                 const unsigned short* __restrict__ Bt,
                                                 unsigned short* __restrict__ Cb,
                                                 float* __restrict__ Cf,
                                                 int M, int N, int K) {
  __shared__ unsigned short sA[128 * 40];
  __shared__ unsigned short sB[128 * 40];
  int t = threadIdx.x;
  int wave = t >> 6, lane = t & 63, quad = lane >> 4, l16 = lane & 15;
  int wm = (wave >> 1) * 64, wn = (wave & 1) * 64;
  long m0 = (long)blockIdx.x * 128, n0 = (long)blockIdx.y * 128;
  f32x4 acc[4][4] = {};
  int srow = t >> 1, sc = (t & 1) * 16;
  const unsigned short* Ag = A + (m0 + srow) * K + sc;
  const unsigned short* Bg = Bt + (n0 + srow) * K + sc;
  unsigned short* sAp = sA + srow * 40 + sc;
  unsigned short* sBp = sB + srow * 40 + sc;
  for (int k0 = 0; k0 < K; k0 += 32) {
    __syncthreads();
    int4 a0 = *(const int4*)(Ag + k0);
    int4 a1 = *(const int4*)(Ag + k0 + 8);
    int4 b0 = *(const int4*)(Bg + k0);
    int4 b1 = *(const int4*)(Bg + k0 + 8);
    *(int4*)(sAp) = a0; *(int4*)(sAp + 8) = a1;
    *(int4*)(sBp) = b0; *(int4*)(sBp + 8) = b1;
    __syncthreads();
    bf16x8 af[4], bfr[4];
#pragma unroll
    for (int i = 0; i < 4; i++) af[i] = *(const bf16x8*)(sA + (wm + i * 16 + l16) * 40 + quad * 8);
#pragma unroll
    for (int j = 0; j < 4; j++) bfr[j] = *(const bf16x8*)(sB + (wn + j * 16 + l16) * 40 + quad * 8);
#pragma unroll
    for (int i = 0; i < 4; i++)
#pragma unroll
      for (int j = 0; j < 4; j++)
        acc[i][j] = __builtin_amdgcn_mfma_f32_16x16x32_bf16(af[i], bfr[j], acc[i][j], 0, 0, 0);
  }
#pragma unroll
  for (int i = 0; i < 4; i++)
#pragma unroll
    for (int j = 0; j < 4; j++)
#pragma unroll
      for (int r = 0; r < 4; r++) {
        long row = m0 + wm + i * 16 + quad * 4 + r;
        long col = n0 + wn + j * 16 + l16;
        float v = acc[i][j][r];
        if (F32OUT) Cf[row * N + col] = v;
        else Cb[row * N + col] = f2bf(v);
      }
}

// ---------------- V [b,s][h*64+d] -> Vt [b,h,d][s] (bf16) ----------------
__global__ __launch_bounds__(256) void k_vtr(const unsigned short* __restrict__ Vp,
                                             unsigned short* __restrict__ Vt) {
  __shared__ unsigned short tile[64][72];
  int b = blockIdx.z, h = blockIdx.y, s0 = blockIdx.x * 64;
  int t = threadIdx.x;
  int r = t >> 2, c = (t & 3) * 16;
  const unsigned short* src = Vp + (long)(b * S + s0 + r) * DM + h * 64;
  *(int4*)(&tile[r][c]) = *(const int4*)(src + c);
  *(int4*)(&tile[r][c + 8]) = *(const int4*)(src + c + 8);
  __syncthreads();
  unsigned short o[16] __attribute__((aligned(16)));
#pragma unroll
  for (int i = 0; i < 16; i++) o[i] = tile[c + i][r];
  unsigned short* dst = Vt + ((long)(b * NH + h) * 64 + r) * S + s0 + c;
  *(int4*)(dst) = *(int4*)(o);
  *(int4*)(dst + 8) = *(int4*)(o + 8);
}

// ---------------- fused attention ----------------
// block: 256 threads (4 waves). grid: (S/16, NH, B). q-block = 16 rows.
__global__ __launch_bounds__(256) void k_attn(const unsigned short* __restrict__ Qb,
                                              const unsigned short* __restrict__ Kb,
                                              const unsigned short* __restrict__ Vt,
                                              const int* __restrict__ mask,
                                              float* __restrict__ attn,
                                              unsigned short* __restrict__ ctx) {
  __shared__ unsigned short sQ[16 * 72];
  __shared__ unsigned short sK[128 * 72];
  __shared__ float sP[16 * 132];
  __shared__ float red[4][16];
  __shared__ float linv[16];
  int b = blockIdx.z, h = blockIdx.y, q0 = blockIdx.x * 16;
  int t = threadIdx.x;
  int wave = t >> 6, lane = t & 63, quad = lane >> 4, l16 = lane & 15;
  {
    int r = t >> 4, c = (t & 15) * 4;
    *(uint2*)(sQ + r * 72 + c) =
        *(const uint2*)(Qb + (long)(b * S + q0 + r) * DM + h * 64 + c);
  }
  const long mbase = (long)b * S * S;
  int krow = t >> 1, kc0 = (t & 1) * 32;
  const unsigned short* Kg = Kb + (long)(b * S + krow) * DM + h * 64 + kc0;
  unsigned short* sKp = sK + krow * 72 + kc0;

  // ---- pass 1: row sums of exp(masked scores) ----
  float lsum[4] = {0.f, 0.f, 0.f, 0.f};
  for (int kt = 0; kt < 16; kt++) {
    __syncthreads();
    {
      const unsigned short* g = Kg + (long)kt * 128 * DM;
      *(int4*)(sKp) = *(const int4*)(g);
      *(int4*)(sKp + 8) = *(const int4*)(g + 8);
      *(int4*)(sKp + 16) = *(const int4*)(g + 16);
      *(int4*)(sKp + 24) = *(const int4*)(g + 24);
    }
    __syncthreads();
    bf16x8 aq0 = *(const bf16x8*)(sQ + l16 * 72 + quad * 8);
    bf16x8 aq1 = *(const bf16x8*)(sQ + l16 * 72 + 32 + quad * 8);
#pragma unroll
    for (int j = 0; j < 2; j++) {
      int kl = wave * 32 + j * 16 + l16;
      bf16x8 bk0 = *(const bf16x8*)(sK + kl * 72 + quad * 8);
      bf16x8 bk1 = *(const bf16x8*)(sK + kl * 72 + 32 + quad * 8);
      f32x4 fa = {0.f, 0.f, 0.f, 0.f};
      fa = __builtin_amdgcn_mfma_f32_16x16x32_bf16(aq0, bk0, fa, 0, 0, 0);
      fa = __builtin_amdgcn_mfma_f32_16x16x32_bf16(aq1, bk1, fa, 0, 0, 0);
      int colg = kt * 128 + kl;
#pragma unroll
      for (int r = 0; r < 4; r++) {
        int rowg = q0 + quad * 4 + r;
        int m = mask[mbase + (long)rowg * S + colg];
        float p = m ? 0.f : __expf(fa[r] * 0.125f);
        lsum[r] += p;
      }
    }
  }
#pragma unroll
  for (int r = 0; r < 4; r++)
    for (int off = 1; off < 16; off <<= 1) lsum[r] += __shfl_xor(lsum[r], off, 64);
  if (l16 == 0)
#pragma unroll
    for (int r = 0; r < 4; r++) red[wave][quad * 4 + r] = lsum[r];
  __syncthreads();
  if (t < 16) linv[t] = 1.f / (red[0][t] + red[1][t] + red[2][t] + red[3][t]);

  // ---- pass 2: recompute, write attn (normalized), accumulate PV ----
  f32x4 oacc = {0.f, 0.f, 0.f, 0.f};
  const unsigned short* vbase = Vt + ((long)(b * NH + h) * 64 + wave * 16 + l16) * S;
  for (int kt = 0; kt < 16; kt++) {
    __syncthreads();
    {
      const unsigned short* g = Kg + (long)kt * 128 * DM;
      *(int4*)(sKp) = *(const int4*)(g);
      *(int4*)(sKp + 8) = *(const int4*)(g + 8);
      *(int4*)(sKp + 16) = *(const int4*)(g + 16);
      *(int4*)(sKp + 24) = *(const int4*)(g + 24);
    }
    __syncthreads();
    bf16x8 aq0 = *(const bf16x8*)(sQ + l16 * 72 + quad * 8);
    bf16x8 aq1 = *(const bf16x8*)(sQ + l16 * 72 + 32 + quad * 8);
#pragma unroll
    for (int j = 0; j < 2; j++) {
      int kl = wave * 32 + j * 16 + l16;
      bf16x8 bk0 = *(const bf16x8*)(sK + kl * 72 + quad * 8);
      bf16x8 bk1 = *(const bf16x8*)(sK + kl * 72 + 32 + quad * 8);
      f32x4 fa = {0.f, 0.f, 0.f, 0.f};
      fa = __builtin_amdgcn_mfma_f32_16x16x32_bf16(aq0, bk0, fa, 0, 0, 0);
      fa = __builtin_amdgcn_mfma_f32_16x16x32_bf16(aq1, bk1, fa, 0, 0, 0);
      int colg = kt * 128 + kl;
#pragma unroll
      for (int r = 0; r < 4; r++) {
        int rowg = q0 + quad * 4 + r;
        int m = mask[mbase + (long)rowg * S + colg];
        float p = m ? 0.f : __expf(fa[r] * 0.125f);
        sP[(quad * 4 + r) * 132 + wave * 32 + j * 16 + l16] = p;
      }
    }
    __syncthreads();
    {  // coalesced fp32 attn write via LDS
      int r = t >> 4, c = (t & 15) * 8;
      float li = linv[r];
      const float* sp = sP + r * 132 + c;
      float4 v0 = *(const float4*)(sp);
      float4 v1 = *(const float4*)(sp + 4);
      v0.x *= li; v0.y *= li; v0.z *= li; v0.w *= li;
      v1.x *= li; v1.y *= li; v1.z *= li; v1.w *= li;
      float* dst = attn + ((long)(b * NH + h) * S + q0 + r) * S + kt * 128 + c;
      *(float4*)(dst) = v0;
      *(float4*)(dst + 4) = v1;
    }
#pragma unroll
    for (int ks = 0; ks < 4; ks++) {
      const float* ap = sP + l16 * 132 + ks * 32 + quad * 8;
      float4 a0 = *(const float4*)(ap);
      float4 a1 = *(const float4*)(ap + 4);
      bf16x8 a8;
      a8[0] = (short)f2bf(a0.x); a8[1] = (short)f2bf(a0.y);
      a8[2] = (short)f2bf(a0.z); a8[3] = (short)f2bf(a0.w);
      a8[4] = (short)f2bf(a1.x); a8[5] = (short)f2bf(a1.y);
      a8[6] = (short)f2bf(a1.z); a8[7] = (short)f2bf(a1.w);
      bf16x8 v8 = *(const bf16x8*)(vbase + kt * 128 + ks * 32 + quad * 8);
      oacc = __builtin_amdgcn_mfma_f32_16x16x32_bf16(a8, v8, oacc, 0, 0, 0);
    }
  }
#pragma unroll
  for (int r = 0; r < 4; r++) {
    int rowg = q0 + quad * 4 + r;
    float v = oacc[r] * linv[quad * 4 + r];
    ctx[((long)(b * S + rowg) * NH + h) * 64 + wave * 16 + l16] = f2bf(v);
  }
}

// ---------------- residual + LayerNorm ----------------
__global__ __launch_bounds__(256) void k_ln(const float* __restrict__ Y,
                                            const float* __restrict__ X,
                                            float* __restrict__ out) {
  __shared__ float rs[4], rs2[4];
  long row = blockIdx.x;
  int t = threadIdx.x;
  float4 v = *(const float4*)(Y + row * DM + t * 4);
  float4 xv = *(const float4*)(X + row * DM + t * 4);
  v.x += xv.x; v.y += xv.y; v.z += xv.z; v.w += xv.w;
  float s = v.x + v.y + v.z + v.w;
  float s2 = v.x * v.x + v.y * v.y + v.z * v.z + v.w * v.w;
  for (int off = 1; off < 64; off <<= 1) {
    s += __shfl_xor(s, off, 64);
    s2 += __shfl_xor(s2, off, 64);
  }
  int wave = t >> 6;
  if ((t & 63) == 0) { rs[wave] = s; rs2[wave] = s2; }
  __syncthreads();
  s = rs[0] + rs[1] + rs[2] + rs[3];
  s2 = rs2[0] + rs2[1] + rs2[2] + rs2[3];
  float mu = s * (1.f / 1024.f);
  float var = s2 * (1.f / 1024.f) - mu * mu;
  float rstd = rsqrtf(var + 1e-5f);
  float4 o;
  o.x = (v.x - mu) * rstd; o.y = (v.y - mu) * rstd;
  o.z = (v.z - mu) * rstd; o.w = (v.w - mu) * rstd;
  *(float4*)(out + row * DM + t * 4) = o;
}

extern "C" void kernel_launch(void* const* d_in, const int* in_sizes, int n_in,
                              void* d_out, int out_size, void* d_ws, size_t ws_size,
                              hipStream_t stream) {
  const float* inQ = (const float*)d_in[0];
  const float* inK = (const float*)d_in[1];
  const float* inV = (const float*)d_in[2];
  const int* mask = (const int*)d_in[3];
  const float* WQ = (const float*)d_in[4];
  const float* WK = (const float*)d_in[5];
  const float* WV = (const float*)d_in[6];
  const float* WO = (const float*)d_in[7];
  float* out = (float*)d_out;
  float* attn = out + (long)B_ * S * DM;  // 4,194,304 floats in

  char* ws = (char*)d_ws;
  const size_t MB = 1048576;
  unsigned short* WtQ = (unsigned short*)(ws + 0 * MB);
  unsigned short* WtK = (unsigned short*)(ws + 2 * MB);
  unsigned short* WtV = (unsigned short*)(ws + 4 * MB);
  unsigned short* WtO = (unsigned short*)(ws + 6 * MB);
  unsigned short* Xq = (unsigned short*)(ws + 8 * MB);
  unsigned short* Xk = (unsigned short*)(ws + 16 * MB);
  unsigned short* Xv = (unsigned short*)(ws + 24 * MB);
  unsigned short* Qb = (unsigned short*)(ws + 32 * MB);
  unsigned short* Kbf = (unsigned short*)(ws + 40 * MB);
  unsigned short* Vp = (unsigned short*)(ws + 48 * MB);
  unsigned short* Vtr = (unsigned short*)(ws + 56 * MB);
  unsigned short* ctx = (unsigned short*)(ws + 24 * MB);  // reuse Xv (dead by then)
  float* Yf = (float*)(ws + 8 * MB);                      // reuse Xq+Xk (dead by then)

  dim3 blk(256);
  int n = B_ * S * DM;  // 4,194,304

  k_wtr<<<dim3(32, 32), blk, 0, stream>>>(WQ, WtQ);
  k_wtr<<<dim3(32, 32), blk, 0, stream>>>(WK, WtK);
  k_wtr<<<dim3(32, 32), blk, 0, stream>>>(WV, WtV);
  k_wtr<<<dim3(32, 32), blk, 0, stream>>>(WO, WtO);
  k_cvt<<<n / 1024, blk, 0, stream>>>(inQ, Xq, n);
  k_cvt<<<n / 1024, blk, 0, stream>>>(inK, Xk, n);
  k_cvt<<<n / 1024, blk, 0, stream>>>(inV, Xv, n);

  k_gemm_nt<0><<<dim3(32, 8), blk, 0, stream>>>(Xq, WtQ, Qb, nullptr, 4096, 1024, 1024);
  k_gemm_nt<0><<<dim3(32, 8), blk, 0, stream>>>(Xk, WtK, Kbf, nullptr, 4096, 1024, 1024);
  k_gemm_nt<0><<<dim3(32, 8), blk, 0, stream>>>(Xv, WtV, Vp, nullptr, 4096, 1024, 1024);

  k_vtr<<<dim3(32, 16, 2), blk, 0, stream>>>(Vp, Vtr);

  k_attn<<<dim3(128, 16, 2), blk, 0, stream>>>(Qb, Kbf, Vtr, mask, attn, ctx);

  k_gemm_nt<1><<<dim3(32, 8), blk, 0, stream>>>(ctx, WtO, nullptr, Yf, 4096, 1024, 1024);

  k_ln<<<B_ * S, blk, 0, stream>>>(Yf, inQ, out);
}

// Round 2
// 821.776 us; speedup vs baseline: 1.2315x; 1.2315x over previous
//
#include <hip/hip_runtime.h>
#include <hip/hip_bf16.h>

typedef __attribute__((ext_vector_type(8))) short bf16x8;
typedef __attribute__((ext_vector_type(4))) float f32x4;

#define S 2048
#define DM 1024
#define NH 16
#define B_ 2

struct __align__(8) us4 { unsigned short a, b, c, d; };

static __device__ __forceinline__ unsigned short f2bf(float f) {
  unsigned int u = __builtin_bit_cast(unsigned int, f);
  u += 0x7fffu + ((u >> 16) & 1u);
  return (unsigned short)(u >> 16);
}

typedef __attribute__((address_space(3))) unsigned int lds_u32;
typedef __attribute__((address_space(1))) unsigned int gbl_u32;
static __device__ __forceinline__ void gl_lds16(const unsigned short* g, short* l) {
  __builtin_amdgcn_global_load_lds((gbl_u32*)(void*)g, (lds_u32*)l, 16, 0, 0);
}

// ---------------- fp32 -> bf16 elementwise ----------------
__global__ __launch_bounds__(256) void k_cvt(const float* __restrict__ x,
                                             unsigned short* __restrict__ y, int n) {
  int i = (blockIdx.x * 256 + threadIdx.x) * 4;
  if (i >= n) return;
  float4 v = *(const float4*)(x + i);
  us4 o; o.a = f2bf(v.x); o.b = f2bf(v.y); o.c = f2bf(v.z); o.d = f2bf(v.w);
  *(us4*)(y + i) = o;
}

// ---------------- W[K][N] fp32 -> Wt[N][K] bf16 ----------------
__global__ __launch_bounds__(256) void k_wtr(const float* __restrict__ W,
                                             unsigned short* __restrict__ Wt) {
  __shared__ float tile[32][33];
  int n0 = blockIdx.x * 32, k0 = blockIdx.y * 32;
  int t = threadIdx.x;
  int r = t >> 3, c = (t & 7) * 4;
  float4 v = *(const float4*)(W + (long)(k0 + r) * DM + n0 + c);
  tile[r][c] = v.x; tile[r][c + 1] = v.y; tile[r][c + 2] = v.z; tile[r][c + 3] = v.w;
  __syncthreads();
  us4 o;
  o.a = f2bf(tile[c][r]); o.b = f2bf(tile[c + 1][r]);
  o.c = f2bf(tile[c + 2][r]); o.d = f2bf(tile[c + 3][r]);
  *(us4*)(Wt + (long)(n0 + r) * DM + k0 + c) = o;
}

// ---------------- mask int32 -> bitmask ----------------
__global__ __launch_bounds__(256) void k_pack(const int* __restrict__ mask,
                                              unsigned int* __restrict__ bits) {
  long gid = (long)blockIdx.x * 256 + threadIdx.x;
  int m = mask[gid];
  unsigned long long bm = __ballot(m != 0);
  if ((threadIdx.x & 63) == 0) *(unsigned long long*)(bits + (gid >> 5)) = bm;
}

// ---------------- NT GEMM (m97-style): C[M,N] = A[M,K] @ Bt[N,K]^T ----------------
// 128x64 tile, BK=64, global_load_lds staging, XOR-swizzled LDS chunks.
template <int F32OUT>
__global__ __launch_bounds__(256) void k_gemm2(const unsigned short* __restrict__ A,
                                               const unsigned short* __restrict__ Bt,
                                               unsigned short* __restrict__ Cb,
                                               float* __restrict__ Cf,
                                               int M, int N, int K) {
  __shared__ __align__(16) char smem[24576];
  short* sA = (short*)smem;             // [128][64] swizzled
  short* sB = (short*)(smem + 16384);   // [64][64] swizzled
  int t = threadIdx.x;
  int wave = t >> 6, lane = t & 63, quad = lane >> 4, l16 = lane & 15;
  int wm = (wave >> 1) * 64, wn = (wave & 1) * 32;
  long m0 = (long)blockIdx.x * 128, n0 = (long)blockIdx.y * 64;
  f32x4 acc[4][2] = {};
  for (int k0 = 0; k0 < K; k0 += 64) {
    __syncthreads();
#pragma unroll
    for (int rr = 0; rr < 6; rr++) {
      int id = rr * 4 + wave;
      if (id < 16) {
        int flat = id * 64 + lane;
        int row = flat >> 3, cp = flat & 7, sw = cp ^ (row & 7);
        gl_lds16(A + (m0 + row) * K + k0 + sw * 8, sA + id * 512);
      } else {
        int c = id - 16;
        int flat = c * 64 + lane;
        int row = flat >> 3, cp = flat & 7, sw = cp ^ (row & 7);
        gl_lds16(Bt + (n0 + row) * K + k0 + sw * 8, sB + c * 512);
      }
    }
    __syncthreads();
#pragma unroll
    for (int kk = 0; kk < 2; kk++) {
      bf16x8 af[4], bf_[2];
#pragma unroll
      for (int i = 0; i < 4; i++)
        af[i] = *(const bf16x8*)(sA + (wm + i * 16 + l16) * 64 + (((kk * 4 + quad) ^ (l16 & 7)) * 8));
#pragma unroll
      for (int j = 0; j < 2; j++)
        bf_[j] = *(const bf16x8*)(sB + (wn + j * 16 + l16) * 64 + (((kk * 4 + quad) ^ (l16 & 7)) * 8));
#pragma unroll
      for (int i = 0; i < 4; i++)
#pragma unroll
        for (int j = 0; j < 2; j++)
          acc[i][j] = __builtin_amdgcn_mfma_f32_16x16x32_bf16(af[i], bf_[j], acc[i][j], 0, 0, 0);
    }
  }
#pragma unroll
  for (int i = 0; i < 4; i++)
#pragma unroll
    for (int j = 0; j < 2; j++)
#pragma unroll
      for (int r = 0; r < 4; r++) {
        long row = m0 + wm + i * 16 + quad * 4 + r;
        long col = n0 + wn + j * 16 + l16;
        float v = acc[i][j][r];
        if (F32OUT) Cf[row * N + col] = v;
        else Cb[row * N + col] = f2bf(v);
      }
}

// ---------------- V [b,s][h*64+d] -> Vt [b,h,d][s] (bf16) ----------------
__global__ __launch_bounds__(256) void k_vtr(const unsigned short* __restrict__ Vp,
                                             unsigned short* __restrict__ Vt) {
  __shared__ unsigned short tile[64][72];
  int b = blockIdx.z, h = blockIdx.y, s0 = blockIdx.x * 64;
  int t = threadIdx.x;
  int r = t >> 2, c = (t & 3) * 16;
  const unsigned short* src = Vp + (long)(b * S + s0 + r) * DM + h * 64;
  *(int4*)(&tile[r][c]) = *(const int4*)(src + c);
  *(int4*)(&tile[r][c + 8]) = *(const int4*)(src + c + 8);
  __syncthreads();
  unsigned short o[16] __attribute__((aligned(16)));
#pragma unroll
  for (int i = 0; i < 16; i++) o[i] = tile[c + i][r];
  unsigned short* dst = Vt + ((long)(b * NH + h) * 64 + r) * S + s0 + c;
  *(int4*)(dst) = *(int4*)(o);
  *(int4*)(dst + 8) = *(int4*)(o + 8);
}

// ---------------- flash pass: ctx + linv ----------------
// grid (S/128, NH, B), 256 threads. q-tile 128, k-tile 64 per iter.
__global__ __launch_bounds__(256) void k_flash(const unsigned short* __restrict__ Qb,
                                               const unsigned short* __restrict__ Kb,
                                               const unsigned short* __restrict__ Vt,
                                               const unsigned int* __restrict__ mbits,
                                               float* __restrict__ linvG,
                                               unsigned short* __restrict__ ctx) {
  __shared__ __align__(16) char smem[52736];
  short* sP = (short*)smem;                                   // [128][72] bf16 (padded)
  short* sQ = (short*)(smem + 18432);                         // [128][64] swizzled
  short* sK = (short*)(smem + 18432 + 16384);                 // [64][64] swizzled
  short* sV = (short*)(smem + 18432 + 16384 + 8192);          // [64 d][64 s] swizzled
  unsigned long long* sM = (unsigned long long*)(smem + 18432 + 16384 + 8192 + 8192);  // [128]
  float* sLi = (float*)(smem + 18432 + 16384 + 8192 + 8192 + 1024);                    // [128]

  const int b = blockIdx.z, h = blockIdx.y, q0 = blockIdx.x * 128;
  const int bh = b * NH + h;
  const int t = threadIdx.x;
  const int wave = t >> 6, lane = t & 63, quad = lane >> 4, l16 = lane & 15;

  // stage Q tile (16 KB, 16 chunks)
#pragma unroll
  for (int rr = 0; rr < 4; rr++) {
    int c = rr * 4 + wave;
    int flat = c * 64 + lane;
    int row = flat >> 3, cp = flat & 7, sw = cp ^ (row & 7);
    gl_lds16(Qb + (long)(b * S + q0 + row) * DM + h * 64 + sw * 8, sQ + c * 512);
  }
  __syncthreads();
  bf16x8 aq[2][2];
#pragma unroll
  for (int i = 0; i < 2; i++)
#pragma unroll
    for (int kk = 0; kk < 2; kk++)
      aq[i][kk] = *(const bf16x8*)(sQ + (wave * 32 + i * 16 + l16) * 64 +
                                   (((kk * 4 + quad) ^ (l16 & 7)) * 8));

  f32x4 oacc[2][4] = {};
  float lsum[2][4] = {};

  for (int kt = 0; kt < 32; kt++) {
    __syncthreads();  // previous PV / sM readers done
#pragma unroll
    for (int rr = 0; rr < 4; rr++) {
      int id = rr * 4 + wave;
      if (id < 8) {
        int flat = id * 64 + lane;
        int row = flat >> 3, cp = flat & 7, sw = cp ^ (row & 7);
        gl_lds16(Kb + (long)(b * S + kt * 64 + row) * DM + h * 64 + sw * 8, sK + id * 512);
      } else {
        int cc = id - 8;
        int flat = cc * 64 + lane;
        int d = flat >> 3, cp = flat & 7, sw = cp ^ (d & 7);
        gl_lds16(Vt + (long)(bh * 64 + d) * S + kt * 64 + sw * 8, sV + cc * 512);
      }
    }
    if (t < 128)
      sM[t] = *(const unsigned long long*)(mbits + ((long)(b * S) + q0 + t) * 64 + kt * 2);
    __syncthreads();  // staging complete
    // QK^T
    f32x4 sacc[2][4] = {};
#pragma unroll
    for (int kk = 0; kk < 2; kk++) {
      bf16x8 bk[4];
#pragma unroll
      for (int j = 0; j < 4; j++)
        bk[j] = *(const bf16x8*)(sK + (j * 16 + l16) * 64 + (((kk * 4 + quad) ^ (l16 & 7)) * 8));
#pragma unroll
      for (int i = 0; i < 2; i++)
#pragma unroll
        for (int j = 0; j < 4; j++)
          sacc[i][j] = __builtin_amdgcn_mfma_f32_16x16x32_bf16(aq[i][kk], bk[j], sacc[i][j], 0, 0, 0);
    }
    // mask + exp -> sP, row-sum accumulate
#pragma unroll
    for (int i = 0; i < 2; i++)
#pragma unroll
      for (int r = 0; r < 4; r++) {
        int rl = wave * 32 + i * 16 + quad * 4 + r;
        unsigned long long mw = sM[rl];
        float ls = 0.f;
#pragma unroll
        for (int j = 0; j < 4; j++) {
          int cb = j * 16 + l16;
          float p = ((mw >> cb) & 1ull) ? 0.f : __expf(sacc[i][j][r] * 0.125f);
          ls += p;
          sP[rl * 72 + cb] = (short)f2bf(p);
        }
        lsum[i][r] += ls;
      }
    __syncthreads();  // sP visible
    // PV
#pragma unroll
    for (int ks = 0; ks < 2; ks++) {
      bf16x8 aP[2], bV[4];
#pragma unroll
      for (int i = 0; i < 2; i++)
        aP[i] = *(const bf16x8*)(sP + (wave * 32 + i * 16 + l16) * 72 + ks * 32 + quad * 8);
#pragma unroll
      for (int j = 0; j < 4; j++)
        bV[j] = *(const bf16x8*)(sV + (j * 16 + l16) * 64 + (((ks * 4 + quad) ^ (l16 & 7)) * 8));
#pragma unroll
      for (int i = 0; i < 2; i++)
#pragma unroll
        for (int j = 0; j < 4; j++)
          oacc[i][j] = __builtin_amdgcn_mfma_f32_16x16x32_bf16(aP[i], bV[j], oacc[i][j], 0, 0, 0);
    }
  }
  // reduce row sums across the 16 col-lanes
#pragma unroll
  for (int i = 0; i < 2; i++)
#pragma unroll
    for (int r = 0; r < 4; r++) {
      float v = lsum[i][r];
      for (int off = 1; off < 16; off <<= 1) v += __shfl_xor(v, off, 64);
      if (l16 == 0) {
        int rl = wave * 32 + i * 16 + quad * 4 + r;
        float li = 1.f / v;
        sLi[rl] = li;
        linvG[(long)bh * S + q0 + rl] = li;
      }
    }
  __syncthreads();
#pragma unroll
  for (int i = 0; i < 2; i++)
#pragma unroll
    for (int r = 0; r < 4; r++) {
      int rl = wave * 32 + i * 16 + quad * 4 + r;
      float li = sLi[rl];
#pragma unroll
      for (int j = 0; j < 4; j++) {
        float v = oacc[i][j][r] * li;
        ctx[((long)(b * S + q0 + rl) * NH + h) * 64 + j * 16 + l16] = f2bf(v);
      }
    }
}

// ---------------- score writer: attn = exp(QK^T/8)*mask*linv ----------------
// grid (S/128, S/128, B*NH), 256 threads, 128x128 tile, K=64 one-shot.
__global__ __launch_bounds__(256) void k_score(const unsigned short* __restrict__ Qb,
                                               const unsigned short* __restrict__ Kb,
                                               const unsigned int* __restrict__ mbits,
                                               const float* __restrict__ linvG,
                                               float* __restrict__ attn) {
  __shared__ __align__(16) char smem[35328];
  short* sQ = (short*)smem;             // [128][64] swizzled
  short* sK = (short*)(smem + 16384);   // [128][64] swizzled
  unsigned long long* sM = (unsigned long long*)(smem + 32768);  // [128][2]
  float* sLi = (float*)(smem + 32768 + 2048);                    // [128]
  int q0 = blockIdx.x * 128, k0 = blockIdx.y * 128, bh = blockIdx.z;
  int b = bh >> 4, h = bh & 15;
  int t = threadIdx.x;
  int wave = t >> 6, lane = t & 63, quad = lane >> 4, l16 = lane & 15;
  int wq = wave >> 1, wk = wave & 1;
#pragma unroll
  for (int rr = 0; rr < 8; rr++) {
    int id = rr * 4 + wave;
    if (id < 16) {
      int flat = id * 64 + lane;
      int row = flat >> 3, cp = flat & 7, sw = cp ^ (row & 7);
      gl_lds16(Qb + (long)(b * S + q0 + row) * DM + h * 64 + sw * 8, sQ + id * 512);
    } else {
      int c = id - 16;
      int flat = c * 64 + lane;
      int row = flat >> 3, cp = flat & 7, sw = cp ^ (row & 7);
      gl_lds16(Kb + (long)(b * S + k0 + row) * DM + h * 64 + sw * 8, sK + c * 512);
    }
  }
  {
    int row = t >> 1, half = t & 1;
    sM[row * 2 + half] =
        *(const unsigned long long*)(mbits + ((long)(b * S) + q0 + row) * 64 + (k0 >> 5) + half * 2);
  }
  if (t < 128) sLi[t] = linvG[(long)bh * S + q0 + t];
  __syncthreads();
  bf16x8 a_[4][2], b_[4][2];
#pragma unroll
  for (int i = 0; i < 4; i++)
#pragma unroll
    for (int kk = 0; kk < 2; kk++)
      a_[i][kk] = *(const bf16x8*)(sQ + (wq * 64 + i * 16 + l16) * 64 +
                                   (((kk * 4 + quad) ^ (l16 & 7)) * 8));
#pragma unroll
  for (int j = 0; j < 4; j++)
#pragma unroll
    for (int kk = 0; kk < 2; kk++)
      b_[j][kk] = *(const bf16x8*)(sK + (wk * 64 + j * 16 + l16) * 64 +
                                   (((kk * 4 + quad) ^ (l16 & 7)) * 8));
  f32x4 sacc[4][4] = {};
#pragma unroll
  for (int kk = 0; kk < 2; kk++)
#pragma unroll
    for (int i = 0; i < 4; i++)
#pragma unroll
      for (int j = 0; j < 4; j++)
        sacc[i][j] = __builtin_amdgcn_mfma_f32_16x16x32_bf16(a_[i][kk], b_[j][kk], sacc[i][j], 0, 0, 0);
#pragma unroll
  for (int i = 0; i < 4; i++)
#pragma unroll
    for (int r = 0; r < 4; r++) {
      int rl = wq * 64 + i * 16 + quad * 4 + r;
      unsigned long long mw = sM[rl * 2 + wk];
      float li = sLi[rl];
      float* dst = attn + ((long)bh * S + q0 + rl) * S + k0 + wk * 64;
#pragma unroll
      for (int j = 0; j < 4; j++) {
        float p = ((mw >> (j * 16 + l16)) & 1ull) ? 0.f : __expf(sacc[i][j][r] * 0.125f) * li;
        dst[j * 16 + l16] = p;
      }
    }
}

// ---------------- residual + LayerNorm ----------------
__global__ __launch_bounds__(256) void k_ln(const float* __restrict__ Y,
                                            const float* __restrict__ X,
                                            float* __restrict__ out) {
  __shared__ float rs[4], rs2[4];
  long row = blockIdx.x;
  int t = threadIdx.x;
  float4 v = *(const float4*)(Y + row * DM + t * 4);
  float4 xv = *(const float4*)(X + row * DM + t * 4);
  v.x += xv.x; v.y += xv.y; v.z += xv.z; v.w += xv.w;
  float s = v.x + v.y + v.z + v.w;
  float s2 = v.x * v.x + v.y * v.y + v.z * v.z + v.w * v.w;
  for (int off = 1; off < 64; off <<= 1) {
    s += __shfl_xor(s, off, 64);
    s2 += __shfl_xor(s2, off, 64);
  }
  int wave = t >> 6;
  if ((t & 63) == 0) { rs[wave] = s; rs2[wave] = s2; }
  __syncthreads();
  s = rs[0] + rs[1] + rs[2] + rs[3];
  s2 = rs2[0] + rs2[1] + rs2[2] + rs2[3];
  float mu = s * (1.f / 1024.f);
  float var = s2 * (1.f / 1024.f) - mu * mu;
  float rstd = rsqrtf(var + 1e-5f);
  float4 o;
  o.x = (v.x - mu) * rstd; o.y = (v.y - mu) * rstd;
  o.z = (v.z - mu) * rstd; o.w = (v.w - mu) * rstd;
  *(float4*)(out + row * DM + t * 4) = o;
}

extern "C" void kernel_launch(void* const* d_in, const int* in_sizes, int n_in,
                              void* d_out, int out_size, void* d_ws, size_t ws_size,
                              hipStream_t stream) {
  const float* inQ = (const float*)d_in[0];
  const float* inK = (const float*)d_in[1];
  const float* inV = (const float*)d_in[2];
  const int* mask = (const int*)d_in[3];
  const float* WQ = (const float*)d_in[4];
  const float* WK = (const float*)d_in[5];
  const float* WV = (const float*)d_in[6];
  const float* WO = (const float*)d_in[7];
  float* out = (float*)d_out;
  float* attn = out + (long)B_ * S * DM;

  char* ws = (char*)d_ws;
  const size_t MB = 1048576;
  unsigned short* WtQ = (unsigned short*)(ws + 0 * MB);
  unsigned short* WtK = (unsigned short*)(ws + 2 * MB);
  unsigned short* WtV = (unsigned short*)(ws + 4 * MB);
  unsigned short* WtO = (unsigned short*)(ws + 6 * MB);
  unsigned short* Xq = (unsigned short*)(ws + 8 * MB);
  unsigned short* Xk = (unsigned short*)(ws + 16 * MB);
  unsigned short* Xv = (unsigned short*)(ws + 24 * MB);
  unsigned short* Qb = (unsigned short*)(ws + 32 * MB);
  unsigned short* Kbf = (unsigned short*)(ws + 40 * MB);
  unsigned short* Vp = (unsigned short*)(ws + 48 * MB);      // dead after k_vtr
  unsigned short* Vtr = (unsigned short*)(ws + 56 * MB);
  unsigned int* mbits = (unsigned int*)(ws + 48 * MB);       // reuse Vp region (1 MB)
  float* linvG = (float*)(ws + 50 * MB);                     // 256 KB, also in Vp region
  unsigned short* ctx = (unsigned short*)(ws + 24 * MB);     // reuse Xv
  float* Yf = (float*)(ws + 8 * MB);                         // reuse Xq+Xk

  dim3 blk(256);
  int n = B_ * S * DM;

  k_wtr<<<dim3(32, 32), blk, 0, stream>>>(WQ, WtQ);
  k_wtr<<<dim3(32, 32), blk, 0, stream>>>(WK, WtK);
  k_wtr<<<dim3(32, 32), blk, 0, stream>>>(WV, WtV);
  k_wtr<<<dim3(32, 32), blk, 0, stream>>>(WO, WtO);
  k_cvt<<<n / 1024, blk, 0, stream>>>(inQ, Xq, n);
  k_cvt<<<n / 1024, blk, 0, stream>>>(inK, Xk, n);
  k_cvt<<<n / 1024, blk, 0, stream>>>(inV, Xv, n);

  k_gemm2<0><<<dim3(32, 16), blk, 0, stream>>>(Xq, WtQ, Qb, nullptr, 4096, 1024, 1024);
  k_gemm2<0><<<dim3(32, 16), blk, 0, stream>>>(Xk, WtK, Kbf, nullptr, 4096, 1024, 1024);
  k_gemm2<0><<<dim3(32, 16), blk, 0, stream>>>(Xv, WtV, Vp, nullptr, 4096, 1024, 1024);

  k_vtr<<<dim3(32, 16, 2), blk, 0, stream>>>(Vp, Vtr);
  k_pack<<<dim3((B_ * S * S) / 256), blk, 0, stream>>>(mask, mbits);  // after k_vtr (aliases Vp)

  k_flash<<<dim3(16, 16, 2), blk, 0, stream>>>(Qb, Kbf, Vtr, mbits, linvG, ctx);
  k_score<<<dim3(16, 16, 32), blk, 0, stream>>>(Qb, Kbf, mbits, linvG, attn);

  k_gemm2<1><<<dim3(32, 16), blk, 0, stream>>>(ctx, WtO, nullptr, Yf, 4096, 1024, 1024);

  k_ln<<<B_ * S, blk, 0, stream>>>(Yf, inQ, out);
}